// Round 13
// baseline (256.015 us; speedup 1.0000x reference)
//
#include <hip/hip_runtime.h>

// cAttention B=8, C=16, L=512, D=256 (fp32 in/out).
// R17 = KERNEL SPLIT of R14 (best 86us): stage1 GEMM+exp -> Es(f16) in ws;
// then score||stage2 kernel reads Es back (L3-hot).
//   A (ca_stage1): R14's stage1 verbatim (BM=32, staged Wqb, 2048 blocks)
//     + Es bounce through the Bs alias -> coalesced 32KB row-major store.
//   B (ca_fused2): R14 minus stage1: prologue = 4 coalesced global_load_lds
//     Es row-loads per wave + x convert; then the proven score||stage2-direct
//     fused phase + out epilogue.
// Mechanism: converts in-block phase serialization (stage1 -> score) into
// two homogeneous kernels that each overlap their own bottleneck across
// blocks. R15 (big tile, 1 blk/CU) and R16 (megaphase, 48-acc spill) showed
// in-kernel fixes are structurally blocked.
// Frozen: scalar-f32 score, full-exp Es clamp +-15, no setprio in tight
// loops (spill trigger, R11/R13), bsc precompute, cvt_pk convert.

typedef __attribute__((ext_vector_type(8))) short bf16x8;
typedef __attribute__((ext_vector_type(4))) float f32x4;
typedef __attribute__((ext_vector_type(8))) _Float16 h16x8;
typedef __attribute__((ext_vector_type(4))) _Float16 h16x4;
typedef const __attribute__((address_space(1))) void* gp1_t;
typedef __attribute__((address_space(3))) void* lp3_t;

__device__ __forceinline__ unsigned short f2bf(float f) {
  union { float f; unsigned int u; } v; v.f = f;
  return (unsigned short)((v.u + 0x7FFFu + ((v.u >> 16) & 1u)) >> 16);
}

__device__ __forceinline__ unsigned int cvt_pk_bf16(float a, float b) {
  unsigned int r;
  asm("v_cvt_pk_bf16_f32 %0, %1, %2" : "=v"(r) : "v"(a), "v"(b));
  return r;  // lo = bf16(a), hi = bf16(b)
}

// ---- prep (unchanged from R14) ----
__global__ __launch_bounds__(256) void ca_prep_kernel(
    const float* __restrict__ Wqkv, const float* __restrict__ Wout,
    const float* __restrict__ bqkv, const float* __restrict__ bh,
    unsigned short* __restrict__ Wqb_t, unsigned short* __restrict__ Wcb_t,
    float* __restrict__ bcomb, float* __restrict__ bsc) {
  const int blk = blockIdx.x;
  if (blk < 64) {
    const int t = blk * 256 + threadIdx.x;  // 16384 threads
    const int k8 = t >> 9, n = t & 511;
    const float* src = Wqkv + (size_t)n * 256 + k8 * 8;
    const float4 v0 = *(const float4*)src;
    const float4 v1 = *(const float4*)(src + 4);
    bf16x8 o;
    o[0] = (short)f2bf(v0.x); o[1] = (short)f2bf(v0.y);
    o[2] = (short)f2bf(v0.z); o[3] = (short)f2bf(v0.w);
    o[4] = (short)f2bf(v1.x); o[5] = (short)f2bf(v1.y);
    o[6] = (short)f2bf(v1.z); o[7] = (short)f2bf(v1.w);
    *(bf16x8*)(Wqb_t + (size_t)t * 8) = o;
    return;
  }
  const int dp = blk - 64;       // output row n (0..255)
  const int e = threadIdx.x;     // k (0..255)
  if (dp < 2) {                  // bsc[512]: scaled combined bias
    const int n = dp * 256 + e;
    const float b = bqkv[n] + (n < 256 ? bh[n] : 0.f);
    bsc[n] = b * 2.8853900817779268f;  // 2*log2(e)
  }
  const float* wrow = Wout + (size_t)dp * 256;
  float acc = 0.f;
  for (int f = 0; f < 256; ++f)
    acc = fmaf(wrow[f], Wqkv[(size_t)(512 + f) * 256 + e], acc);
  Wcb_t[((size_t)(e >> 3) * 256 + dp) * 8 + (e & 7)] = f2bf(acc);
  if (e == 0) {
    float b = 0.f;
    for (int f = 0; f < 256; ++f) b = fmaf(wrow[f], bqkv[512 + f], b);
    bcomb[dp] = b;
  }
}

// ---- kernel A: stage1 GEMM + exp -> Es_g[r][512] f16 (row-major) ----
__global__ __launch_bounds__(512, 6) void ca_stage1(
    const float* __restrict__ x,               // (8,16,512,256) fp32
    const unsigned short* __restrict__ Wqb_t,  // [32][512][8] bf16
    const float* __restrict__ bsc,             // 512: (bias)*2log2e
    unsigned short* __restrict__ Es_g) {       // 65536 x 512 f16 bits
  __shared__ __align__(16) unsigned short xs[32 * 264];  // 16.9 KB A tile
  __shared__ __align__(16) unsigned short BsEs[16640];   // 33.3 KB Bs/Es alias
  unsigned short* const Bs = BsEs;
  _Float16* const Es = (_Float16*)BsEs;     // 32 rows x 520

  const int tid = threadIdx.x;
  const int lane = tid & 63, wave = tid >> 6;
  const int quad = lane >> 4, l15 = lane & 15;
  const int rt0 = blockIdx.x * 32;

  // issue k0c=0 B loads (2048 x 16B segs, lane-linear into Bs)
#pragma unroll
  for (int i = 0; i < 4; ++i) {
    const int sb = wave * 256 + i * 64;
    const unsigned short* g = Wqb_t + (size_t)(sb + lane) * 8;
    __builtin_amdgcn_global_load_lds((gp1_t)g, (lp3_t)(Bs + sb * 8), 16, 0, 0);
  }

  // x tile: 32 rows x 256 fp32 -> bf16 -> xs (row stride 264)
  {
    const int rl = tid >> 4, c0 = (tid & 15) * 16;
    const int r = rt0 + rl;
    const int b = r >> 13, l = (r >> 4) & 511, c = r & 15;
    const float* src = x + ((size_t)(b * 16 + c) * 512 + l) * 256 + c0;
    unsigned short* dst = xs + rl * 264 + c0;
#pragma unroll
    for (int j = 0; j < 2; ++j) {
      const float4 v0 = *(const float4*)(src + j * 8);
      const float4 v1 = *(const float4*)(src + j * 8 + 4);
      uint4 o;
      o.x = cvt_pk_bf16(v0.x, v0.y);
      o.y = cvt_pk_bf16(v0.z, v0.w);
      o.z = cvt_pk_bf16(v1.x, v1.y);
      o.w = cvt_pk_bf16(v1.z, v1.w);
      *(uint4*)(dst + j * 8) = o;
    }
  }
  __syncthreads();  // xs ready; k0c=0 B tile landed

  // stage 1 K-loop (R14 verbatim)
  f32x4 acc[2][4] = {};
  for (int k0c = 0; k0c < 8; ++k0c) {
    bf16x8 af[2], bfr[4];
#pragma unroll
    for (int mi = 0; mi < 2; ++mi)
      af[mi] = *(const bf16x8*)&xs[(mi * 16 + l15) * 264 + k0c * 32 + quad * 8];
#pragma unroll
    for (int ni = 0; ni < 4; ++ni)
      bfr[ni] = *(const bf16x8*)&Bs[(quad * 512 + wave * 64 + ni * 16 + l15) * 8];
    __syncthreads();  // frags in regs; Bs free for next tile
    if (k0c < 7) {
#pragma unroll
      for (int i = 0; i < 4; ++i) {
        const int sb = wave * 256 + i * 64;
        const unsigned short* g =
            Wqb_t + ((size_t)(k0c + 1) * 2048 + sb + lane) * 8;
        __builtin_amdgcn_global_load_lds((gp1_t)g, (lp3_t)(Bs + sb * 8), 16, 0, 0);
      }
    }
#pragma unroll
    for (int mi = 0; mi < 2; ++mi)
#pragma unroll
      for (int ni = 0; ni < 4; ++ni)
        acc[mi][ni] = __builtin_amdgcn_mfma_f32_16x16x32_bf16(
            bfr[ni], af[mi], acc[mi][ni], 0, 0, 0);
    __syncthreads();  // drains vmcnt: next tile ready
  }

  // epilogue: E = exp2(clamp(acc*2log2e + bsc, +-15)) -> Es (LDS bounce)
  const float SC = 2.8853900817779268f;  // 2*log2(e)
#pragma unroll
  for (int mi = 0; mi < 2; ++mi) {
    const int rl = mi * 16 + l15;
#pragma unroll
    for (int ni = 0; ni < 4; ++ni) {
      const int n = wave * 64 + ni * 16 + quad * 4;
      const float4 bs = *(const float4*)(bsc + n);
      h16x4 st;
      st[0] = (_Float16)__builtin_amdgcn_exp2f(
          fminf(15.f, fmaxf(-15.f, fmaf(acc[mi][ni][0], SC, bs.x))));
      st[1] = (_Float16)__builtin_amdgcn_exp2f(
          fminf(15.f, fmaxf(-15.f, fmaf(acc[mi][ni][1], SC, bs.y))));
      st[2] = (_Float16)__builtin_amdgcn_exp2f(
          fminf(15.f, fmaxf(-15.f, fmaf(acc[mi][ni][2], SC, bs.z))));
      st[3] = (_Float16)__builtin_amdgcn_exp2f(
          fminf(15.f, fmaxf(-15.f, fmaf(acc[mi][ni][3], SC, bs.w))));
      *(h16x4*)&Es[rl * 520 + n] = st;
    }
  }
  __syncthreads();  // Es bounce complete

  // coalesced store: 32 rows x 1KB -> Es_g[rt0+row][0..511]
  {
    const int row = tid >> 4, c0 = (tid & 15) * 32;  // 64B per thread
    const unsigned short* srcE = BsEs + row * 520 + c0;
    unsigned short* dstE = Es_g + (size_t)(rt0 + row) * 512 + c0;
#pragma unroll
    for (int j = 0; j < 4; ++j)
      *(uint4*)(dstE + j * 8) = *(const uint4*)(srcE + j * 8);
  }
}

// ---- kernel B: score || stage2 (direct Wcb) + out ----
__global__ __launch_bounds__(512, 6) void ca_fused2(
    const float* __restrict__ x,               // (8,16,512,256) fp32
    const unsigned short* __restrict__ Es_g,   // 65536 x 512 f16
    const unsigned short* __restrict__ Wcb_t,  // [32][256][8] bf16
    const float* __restrict__ Vw,
    const float* __restrict__ bcomb, const float* __restrict__ bout,
    float* __restrict__ out) {
  __shared__ __align__(16) unsigned short xs[32 * 264];   // 16.9 KB
  __shared__ __align__(16) unsigned short EsL[32 * 520];  // 33.3 KB
  __shared__ __align__(16) float vw_s[256];
  __shared__ float af_s[32];
  const _Float16* const Es = (const _Float16*)EsL;

  const int tid = threadIdx.x;
  const int lane = tid & 63, wave = tid >> 6;
  const int quad = lane >> 4, l15 = lane & 15;
  const int rt0 = blockIdx.x * 32;

  // issue Es row-loads: 1 row (1KB) per wave-instruction, 4 rows/wave
#pragma unroll
  for (int i = 0; i < 4; ++i) {
    const int row = wave * 4 + i;
    const unsigned short* g = Es_g + (size_t)(rt0 + row) * 512 + lane * 8;
    __builtin_amdgcn_global_load_lds((gp1_t)g, (lp3_t)(EsL + row * 520), 16, 0, 0);
  }

  if (tid < 256) vw_s[tid] = -2.f * Vw[tid];

  // x tile: 32 rows x 256 fp32 -> bf16 -> xs (row stride 264)
  {
    const int rl = tid >> 4, c0 = (tid & 15) * 16;
    const int r = rt0 + rl;
    const int b = r >> 13, l = (r >> 4) & 511, c = r & 15;
    const float* src = x + ((size_t)(b * 16 + c) * 512 + l) * 256 + c0;
    unsigned short* dst = xs + rl * 264 + c0;
#pragma unroll
    for (int j = 0; j < 2; ++j) {
      const float4 v0 = *(const float4*)(src + j * 8);
      const float4 v1 = *(const float4*)(src + j * 8 + 4);
      uint4 o;
      o.x = cvt_pk_bf16(v0.x, v0.y);
      o.y = cvt_pk_bf16(v0.z, v0.w);
      o.z = cvt_pk_bf16(v1.x, v1.y);
      o.w = cvt_pk_bf16(v1.z, v1.w);
      *(uint4*)(dst + j * 8) = o;
    }
  }
  __syncthreads();  // EsL landed (barrier drains vmcnt); xs + vw_s ready

  // fused: score (VALU) || stage 2 (MFMA + L2 B-fetch)  [R14 verbatim]
  f32x4 acc2[2][2] = {};
  {
    const int p = tid >> 8, qc = (tid >> 4) & 15, kc = tid & 15;
    const _Float16* eqp = Es + (p * 16 + qc) * 520;
    const _Float16* ekp = Es + (p * 16 + kc) * 520 + 256;
    const unsigned short* wb2 = Wcb_t + (size_t)(quad * 256 + wave * 32 + l15) * 8;
    bf16x8 bcur0 = *(const bf16x8*)(wb2);
    bf16x8 bcur1 = *(const bf16x8*)(wb2 + 128);
    f32x4 a4 = {};
#pragma unroll
    for (int c = 0; c < 8; ++c) {
      bf16x8 bnxt0, bnxt1;
      if (c < 7) {  // prefetch next chunk's B-frags (covered by score VALU)
        bnxt0 = *(const bf16x8*)(wb2 + (size_t)(c + 1) * 8192);
        bnxt1 = *(const bf16x8*)(wb2 + (size_t)(c + 1) * 8192 + 128);
      }
      bf16x8 af0 = *(const bf16x8*)&xs[l15 * 264 + c * 32 + quad * 8];
      bf16x8 af1 = *(const bf16x8*)&xs[(16 + l15) * 264 + c * 32 + quad * 8];
#pragma unroll
      for (int j = 0; j < 4; ++j) {
        const int d = c * 32 + j * 8;
        const h16x8 eq = *(const h16x8*)(eqp + d);
        const h16x8 ek = *(const h16x8*)(ekp + d);
        const f32x4 wv0 = *(const f32x4*)(vw_s + d);
        const f32x4 wv1 = *(const f32x4*)(vw_s + d + 4);
        f32x4 sg0, sg1;
        sg0.x = __builtin_amdgcn_rcpf(1.f + (float)eq[0] * (float)ek[0]);
        sg0.y = __builtin_amdgcn_rcpf(1.f + (float)eq[1] * (float)ek[1]);
        sg0.z = __builtin_amdgcn_rcpf(1.f + (float)eq[2] * (float)ek[2]);
        sg0.w = __builtin_amdgcn_rcpf(1.f + (float)eq[3] * (float)ek[3]);
        sg1.x = __builtin_amdgcn_rcpf(1.f + (float)eq[4] * (float)ek[4]);
        sg1.y = __builtin_amdgcn_rcpf(1.f + (float)eq[5] * (float)ek[5]);
        sg1.z = __builtin_amdgcn_rcpf(1.f + (float)eq[6] * (float)ek[6]);
        sg1.w = __builtin_amdgcn_rcpf(1.f + (float)eq[7] * (float)ek[7]);
        a4 += wv0 * sg0 + wv1 * sg1;
      }
      acc2[0][0] = __builtin_amdgcn_mfma_f32_16x16x32_bf16(bcur0, af0, acc2[0][0], 0, 0, 0);
      acc2[0][1] = __builtin_amdgcn_mfma_f32_16x16x32_bf16(bcur1, af0, acc2[0][1], 0, 0, 0);
      acc2[1][0] = __builtin_amdgcn_mfma_f32_16x16x32_bf16(bcur0, af1, acc2[1][0], 0, 0, 0);
      acc2[1][1] = __builtin_amdgcn_mfma_f32_16x16x32_bf16(bcur1, af1, acc2[1][1], 0, 0, 0);
      bcur0 = bnxt0; bcur1 = bnxt1;
    }
    float s = (a4[0] + a4[1]) + (a4[2] + a4[3]);
    float m = s;
    for (int off = 8; off; off >>= 1) m = fmaxf(m, __shfl_xor(m, off, 16));
    const float e = __builtin_amdgcn_exp2f((s - m) * 1.4426950408889634f);
    float sum = e;
    for (int off = 8; off; off >>= 1) sum += __shfl_xor(sum, off, 16);
    if (kc == qc) af_s[p * 16 + qc] = e / sum;
  }
  __syncthreads();  // af_s visible

  // out epilogue: out = a*(acc2+bcomb)+bout, permuted (b,c,l,d) store
#pragma unroll
  for (int mi = 0; mi < 2; ++mi) {
    const int rl = mi * 16 + l15;
    const int r = rt0 + rl;
    const int c = r & 15, p = r >> 4;
    const int l = p & 511, b = p >> 9;
    const float av = af_s[rl];
    float* orow = out + ((size_t)(b * 16 + c) * 512 + l) * 256;
#pragma unroll
    for (int ni = 0; ni < 2; ++ni) {
      const int n = wave * 32 + ni * 16 + quad * 4;
      const float4 bc = *(const float4*)(bcomb + n);
      const float4 bo = *(const float4*)(bout + n);
      float4 o;
      o.x = fmaf(av, acc2[mi][ni][0] + bc.x, bo.x);
      o.y = fmaf(av, acc2[mi][ni][1] + bc.y, bo.y);
      o.z = fmaf(av, acc2[mi][ni][2] + bc.z, bo.z);
      o.w = fmaf(av, acc2[mi][ni][3] + bc.w, bo.w);
      *(float4*)(orow + n) = o;
    }
  }
}

extern "C" void kernel_launch(void* const* d_in, const int* in_sizes, int n_in,
                              void* d_out, int out_size, void* d_ws, size_t ws_size,
                              hipStream_t stream) {
  (void)in_sizes; (void)n_in; (void)out_size; (void)ws_size;
  const float* x    = (const float*)d_in[0];
  const float* Wqkv = (const float*)d_in[1];
  const float* bqkv = (const float*)d_in[2];
  const float* Vw   = (const float*)d_in[3];
  const float* bh   = (const float*)d_in[5];
  const float* Wout = (const float*)d_in[7];
  const float* bout = (const float*)d_in[8];
  float* out = (float*)d_out;

  // ws: bcomb f32 256 | bsc f32 512 | Wqb_t bf16 512*256 | Wcb_t bf16 256*256
  //     | Es_g f16 65536*512 (64 MB)
  float* bcomb = (float*)d_ws;
  float* bsc = bcomb + 256;
  unsigned short* Wqb_t = (unsigned short*)(bsc + 512);
  unsigned short* Wcb_t = Wqb_t + (size_t)512 * 256;
  unsigned short* Es_g = Wcb_t + (size_t)256 * 256;

  ca_prep_kernel<<<dim3(320), dim3(256), 0, stream>>>(
      Wqkv, Wout, bqkv, bh, Wqb_t, Wcb_t, bcomb, bsc);
  ca_stage1<<<dim3(2048), dim3(512), 0, stream>>>(x, Wqb_t, bsc, Es_g);
  ca_fused2<<<dim3(2048), dim3(512), 0, stream>>>(
      x, Es_g, Wcb_t, Vw, bcomb, bout, out);
}

// Round 14
// 187.684 us; speedup vs baseline: 1.3641x; 1.3641x over previous
//
#include <hip/hip_runtime.h>

// cAttention B=8, C=16, L=512, D=256 (fp32 in/out).
// R18 = R14 (best: 86us) with stage1's staged loop replaced by BARRIER-FREE
// depth-2 register streaming (the clean version of R7's failed idea):
//   R17 measured stage1 ALONE = 92us at 7% MFMA / 9% VALU -- stage1's
//   barrier-convoyed L2 stream IS the whole kernel cost; score||stage2 is
//   already free under it. R7 failed with depth-1 (zero net latency cover)
//   + partial spill (WRITE 96MB under the 85-VGPR cap).
//   Fix: 3-slot rotating B-buffer bb[3][4] (issue chunk c+2 before chunk c's
//   MFMAs = ~400cy cover > L2 latency), ZERO in-loop barriers (was 16),
//   __launch_bounds__(512,4) = 128-VGPR budget (~100 live, no spill).
//   Cost: 2 blocks/CU (vs 3). Spill tripwire: WRITE_SIZE >= 120MB -> revert.
// Frozen: scalar-f32 score, full-exp Es clamp +-15, bsc precompute, cvt_pk
// convert, NO setprio in tight loops (R11/R13 spill trigger).

typedef __attribute__((ext_vector_type(8))) short bf16x8;
typedef __attribute__((ext_vector_type(4))) float f32x4;
typedef __attribute__((ext_vector_type(8))) _Float16 h16x8;
typedef __attribute__((ext_vector_type(4))) _Float16 h16x4;

__device__ __forceinline__ unsigned short f2bf(float f) {
  union { float f; unsigned int u; } v; v.f = f;
  return (unsigned short)((v.u + 0x7FFFu + ((v.u >> 16) & 1u)) >> 16);
}

__device__ __forceinline__ unsigned int cvt_pk_bf16(float a, float b) {
  unsigned int r;
  asm("v_cvt_pk_bf16_f32 %0, %1, %2" : "=v"(r) : "v"(a), "v"(b));
  return r;  // lo = bf16(a), hi = bf16(b)
}

// ---- prep (unchanged from R14) ----
__global__ __launch_bounds__(256) void ca_prep_kernel(
    const float* __restrict__ Wqkv, const float* __restrict__ Wout,
    const float* __restrict__ bqkv, const float* __restrict__ bh,
    unsigned short* __restrict__ Wqb_t, unsigned short* __restrict__ Wcb_t,
    float* __restrict__ bcomb, float* __restrict__ bsc) {
  const int blk = blockIdx.x;
  if (blk < 64) {
    const int t = blk * 256 + threadIdx.x;  // 16384 threads
    const int k8 = t >> 9, n = t & 511;
    const float* src = Wqkv + (size_t)n * 256 + k8 * 8;
    const float4 v0 = *(const float4*)src;
    const float4 v1 = *(const float4*)(src + 4);
    bf16x8 o;
    o[0] = (short)f2bf(v0.x); o[1] = (short)f2bf(v0.y);
    o[2] = (short)f2bf(v0.z); o[3] = (short)f2bf(v0.w);
    o[4] = (short)f2bf(v1.x); o[5] = (short)f2bf(v1.y);
    o[6] = (short)f2bf(v1.z); o[7] = (short)f2bf(v1.w);
    *(bf16x8*)(Wqb_t + (size_t)t * 8) = o;
    return;
  }
  const int dp = blk - 64;       // output row n (0..255)
  const int e = threadIdx.x;     // k (0..255)
  if (dp < 2) {                  // bsc[512]: scaled combined bias
    const int n = dp * 256 + e;
    const float b = bqkv[n] + (n < 256 ? bh[n] : 0.f);
    bsc[n] = b * 2.8853900817779268f;  // 2*log2(e)
  }
  const float* wrow = Wout + (size_t)dp * 256;
  float acc = 0.f;
  for (int f = 0; f < 256; ++f)
    acc = fmaf(wrow[f], Wqkv[(size_t)(512 + f) * 256 + e], acc);
  Wcb_t[((size_t)(e >> 3) * 256 + dp) * 8 + (e & 7)] = f2bf(acc);
  if (e == 0) {
    float b = 0.f;
    for (int f = 0; f < 256; ++f) b = fmaf(wrow[f], bqkv[512 + f], b);
    bcomb[dp] = b;
  }
}

// ---- fused: qk MFMA (barrier-free direct-B) + exp + (score || out MFMA) ----
__global__ __launch_bounds__(512, 4) void ca_fused(
    const float* __restrict__ x,               // (8,16,512,256) fp32
    const unsigned short* __restrict__ Wqb_t,  // [32][512][8] bf16
    const unsigned short* __restrict__ Wcb_t,  // [32][256][8] bf16
    const float* __restrict__ bsc,             // 512: (bias)*2log2e
    const float* __restrict__ Vw,
    const float* __restrict__ bcomb, const float* __restrict__ bout,
    float* __restrict__ out) {
  __shared__ __align__(16) unsigned short xs[32 * 264];  // 16.9 KB A tile
  __shared__ __align__(16) unsigned short EsB[16640];    // 33.3 KB Es
  __shared__ __align__(16) float vw_s[256];
  __shared__ float af_s[32];
  _Float16* const Es = (_Float16*)EsB;      // 32 rows x 520 (512 + pad)

  const int tid = threadIdx.x;
  const int lane = tid & 63, wave = tid >> 6;
  const int quad = lane >> 4, l15 = lane & 15;
  const int rt0 = blockIdx.x * 32;          // global xf row base

  if (tid < 256) vw_s[tid] = -2.f * Vw[tid];

  // x tile: 32 rows x 256 fp32 -> bf16 -> xs (row stride 264)
  {
    const int rl = tid >> 4, c0 = (tid & 15) * 16;
    const int r = rt0 + rl;
    const int b = r >> 13, l = (r >> 4) & 511, c = r & 15;
    const float* src = x + ((size_t)(b * 16 + c) * 512 + l) * 256 + c0;
    unsigned short* dst = xs + rl * 264 + c0;
#pragma unroll
    for (int j = 0; j < 2; ++j) {
      const float4 v0 = *(const float4*)(src + j * 8);
      const float4 v1 = *(const float4*)(src + j * 8 + 4);
      uint4 o;
      o.x = cvt_pk_bf16(v0.x, v0.y);
      o.y = cvt_pk_bf16(v0.z, v0.w);
      o.z = cvt_pk_bf16(v1.x, v1.y);
      o.w = cvt_pk_bf16(v1.z, v1.w);
      *(uint4*)(dst + j * 8) = o;
    }
  }
  __syncthreads();  // xs + vw_s ready

  // ---------- stage 1: E[32 x 512], BARRIER-FREE depth-2 streaming ----------
  // wave owns n-slice [wave*64, wave*64+64); lane reads 16B at
  // b1 + c*16384 + ni*128 (quarter-wave = 256B contiguous).
  f32x4 acc[2][4] = {};
  {
    const unsigned short* b1 = Wqb_t + quad * 4096 + (wave * 64 + l15) * 8;
    bf16x8 bb[3][4];
#pragma unroll
    for (int s = 0; s < 2; ++s)
#pragma unroll
      for (int ni = 0; ni < 4; ++ni)
        bb[s][ni] = *(const bf16x8*)(b1 + (size_t)s * 16384 + ni * 128);
#pragma unroll
    for (int c = 0; c < 8; ++c) {
      if (c + 2 < 8) {
#pragma unroll
        for (int ni = 0; ni < 4; ++ni)
          bb[(c + 2) % 3][ni] =
              *(const bf16x8*)(b1 + (size_t)(c + 2) * 16384 + ni * 128);
      }
      bf16x8 af[2];
#pragma unroll
      for (int mi = 0; mi < 2; ++mi)
        af[mi] = *(const bf16x8*)&xs[(mi * 16 + l15) * 264 + c * 32 + quad * 8];
#pragma unroll
      for (int mi = 0; mi < 2; ++mi)
#pragma unroll
        for (int ni = 0; ni < 4; ++ni)
          acc[mi][ni] = __builtin_amdgcn_mfma_f32_16x16x32_bf16(
              bb[c % 3][ni], af[mi], acc[mi][ni], 0, 0, 0);
    }
  }

  // stage-1 epilogue: E = exp2(clamp(acc*2log2e + bsc, +-15)) -> Es
  const float SC = 2.8853900817779268f;  // 2*log2(e)
#pragma unroll
  for (int mi = 0; mi < 2; ++mi) {
    const int rl = mi * 16 + l15;
#pragma unroll
    for (int ni = 0; ni < 4; ++ni) {
      const int n = wave * 64 + ni * 16 + quad * 4;
      const float4 bs = *(const float4*)(bsc + n);
      h16x4 st;
      st[0] = (_Float16)__builtin_amdgcn_exp2f(
          fminf(15.f, fmaxf(-15.f, fmaf(acc[mi][ni][0], SC, bs.x))));
      st[1] = (_Float16)__builtin_amdgcn_exp2f(
          fminf(15.f, fmaxf(-15.f, fmaf(acc[mi][ni][1], SC, bs.y))));
      st[2] = (_Float16)__builtin_amdgcn_exp2f(
          fminf(15.f, fmaxf(-15.f, fmaf(acc[mi][ni][2], SC, bs.z))));
      st[3] = (_Float16)__builtin_amdgcn_exp2f(
          fminf(15.f, fmaxf(-15.f, fmaf(acc[mi][ni][3], SC, bs.w))));
      *(h16x4*)&Es[rl * 520 + n] = st;
    }
  }
  __syncthreads();  // Es visible to all waves

  // ---------- fused: score (VALU) || stage 2 (MFMA + L2 B-fetch) ----------
  f32x4 acc2[2][2] = {};
  {
    const int p = tid >> 8, qc = (tid >> 4) & 15, kc = tid & 15;
    const _Float16* eqp = Es + (p * 16 + qc) * 520;
    const _Float16* ekp = Es + (p * 16 + kc) * 520 + 256;
    const unsigned short* wb2 = Wcb_t + (size_t)(quad * 256 + wave * 32 + l15) * 8;
    bf16x8 bcur0 = *(const bf16x8*)(wb2);
    bf16x8 bcur1 = *(const bf16x8*)(wb2 + 128);
    f32x4 a4 = {};
#pragma unroll
    for (int c = 0; c < 8; ++c) {
      bf16x8 bnxt0, bnxt1;
      if (c < 7) {  // prefetch next chunk's B-frags (covered by score VALU)
        bnxt0 = *(const bf16x8*)(wb2 + (size_t)(c + 1) * 8192);
        bnxt1 = *(const bf16x8*)(wb2 + (size_t)(c + 1) * 8192 + 128);
      }
      bf16x8 af0 = *(const bf16x8*)&xs[l15 * 264 + c * 32 + quad * 8];
      bf16x8 af1 = *(const bf16x8*)&xs[(16 + l15) * 264 + c * 32 + quad * 8];
      // 4 score iterations over d = 32c .. 32c+31 (scalar-f32 form: frozen)
#pragma unroll
      for (int j = 0; j < 4; ++j) {
        const int d = c * 32 + j * 8;
        const h16x8 eq = *(const h16x8*)(eqp + d);
        const h16x8 ek = *(const h16x8*)(ekp + d);
        const f32x4 wv0 = *(const f32x4*)(vw_s + d);
        const f32x4 wv1 = *(const f32x4*)(vw_s + d + 4);
        f32x4 sg0, sg1;
        sg0.x = __builtin_amdgcn_rcpf(1.f + (float)eq[0] * (float)ek[0]);
        sg0.y = __builtin_amdgcn_rcpf(1.f + (float)eq[1] * (float)ek[1]);
        sg0.z = __builtin_amdgcn_rcpf(1.f + (float)eq[2] * (float)ek[2]);
        sg0.w = __builtin_amdgcn_rcpf(1.f + (float)eq[3] * (float)ek[3]);
        sg1.x = __builtin_amdgcn_rcpf(1.f + (float)eq[4] * (float)ek[4]);
        sg1.y = __builtin_amdgcn_rcpf(1.f + (float)eq[5] * (float)ek[5]);
        sg1.z = __builtin_amdgcn_rcpf(1.f + (float)eq[6] * (float)ek[6]);
        sg1.w = __builtin_amdgcn_rcpf(1.f + (float)eq[7] * (float)ek[7]);
        a4 += wv0 * sg0 + wv1 * sg1;
      }
      acc2[0][0] = __builtin_amdgcn_mfma_f32_16x16x32_bf16(bcur0, af0, acc2[0][0], 0, 0, 0);
      acc2[0][1] = __builtin_amdgcn_mfma_f32_16x16x32_bf16(bcur1, af0, acc2[0][1], 0, 0, 0);
      acc2[1][0] = __builtin_amdgcn_mfma_f32_16x16x32_bf16(bcur0, af1, acc2[1][0], 0, 0, 0);
      acc2[1][1] = __builtin_amdgcn_mfma_f32_16x16x32_bf16(bcur1, af1, acc2[1][1], 0, 0, 0);
      bcur0 = bnxt0; bcur1 = bnxt1;
    }
    // score reduction + diagonal softmax weight
    float s = (a4[0] + a4[1]) + (a4[2] + a4[3]);
    float m = s;
    for (int off = 8; off; off >>= 1) m = fmaxf(m, __shfl_xor(m, off, 16));
    const float e = __builtin_amdgcn_exp2f((s - m) * 1.4426950408889634f);
    float sum = e;
    for (int off = 8; off; off >>= 1) sum += __shfl_xor(sum, off, 16);
    if (kc == qc) af_s[p * 16 + qc] = e / sum;
  }
  __syncthreads();  // af_s visible to all waves

  // stage-2 epilogue: out = a*(acc2+bcomb)+bout, permuted (b,c,l,d) store
#pragma unroll
  for (int mi = 0; mi < 2; ++mi) {
    const int rl = mi * 16 + l15;
    const int r = rt0 + rl;
    const int c = r & 15, p = r >> 4;
    const int l = p & 511, b = p >> 9;
    const float av = af_s[rl];
    float* orow = out + ((size_t)(b * 16 + c) * 512 + l) * 256;
#pragma unroll
    for (int ni = 0; ni < 2; ++ni) {
      const int n = wave * 32 + ni * 16 + quad * 4;
      const float4 bc = *(const float4*)(bcomb + n);
      const float4 bo = *(const float4*)(bout + n);
      float4 o;
      o.x = fmaf(av, acc2[mi][ni][0] + bc.x, bo.x);
      o.y = fmaf(av, acc2[mi][ni][1] + bc.y, bo.y);
      o.z = fmaf(av, acc2[mi][ni][2] + bc.z, bo.z);
      o.w = fmaf(av, acc2[mi][ni][3] + bc.w, bo.w);
      *(float4*)(orow + n) = o;
    }
  }
}

extern "C" void kernel_launch(void* const* d_in, const int* in_sizes, int n_in,
                              void* d_out, int out_size, void* d_ws, size_t ws_size,
                              hipStream_t stream) {
  (void)in_sizes; (void)n_in; (void)out_size; (void)ws_size;
  const float* x    = (const float*)d_in[0];
  const float* Wqkv = (const float*)d_in[1];
  const float* bqkv = (const float*)d_in[2];
  const float* Vw   = (const float*)d_in[3];
  const float* bh   = (const float*)d_in[5];
  const float* Wout = (const float*)d_in[7];
  const float* bout = (const float*)d_in[8];
  float* out = (float*)d_out;

  // ws: bcomb f32 256 | bsc f32 512 | Wqb_t bf16 512*256 | Wcb_t bf16 256*256
  float* bcomb = (float*)d_ws;
  float* bsc = bcomb + 256;
  unsigned short* Wqb_t = (unsigned short*)(bsc + 512);
  unsigned short* Wcb_t = Wqb_t + (size_t)512 * 256;

  ca_prep_kernel<<<dim3(320), dim3(256), 0, stream>>>(
      Wqkv, Wout, bqkv, bh, Wqb_t, Wcb_t, bcomb, bsc);
  ca_fused<<<dim3(2048), dim3(512), 0, stream>>>(
      x, Wqb_t, Wcb_t, bsc, Vw, bcomb, bout, out);
}

// Round 15
// 183.132 us; speedup vs baseline: 1.3980x; 1.0249x over previous
//
#include <hip/hip_runtime.h>

// cAttention B=8, C=16, L=512, D=256 (fp32 in/out).
// R19 = R18 (best: 79us fused; barrier-free depth-2 stage1 streaming) +
//       4-way BATCHED RECIPROCAL in the score, pure scalar-f32 form:
//   sum_i w_i/A_i = num/(A0*A1*A2*A3), ONE v_rcp_f32 per 4 elements (was 4).
//   rcp is quarter-rate: per-8-elem issue ~64 -> ~50 cy.
//   ATTRIBUTION FIX: R13 proved R11's spill trigger was setprio, NOT the
//   batched rcp -- the batched form was never cleanly tested. R12's packed-
//   f16 front-end (separate regression) is NOT used here: front end stays
//   scalar-f32 cvt+fma. Temps die within each 4-group; asum scalar replaces
//   the a4 vector. No setprio anywhere (R11/R13 spill rule).
//   Range: Es in [2^-15,2^15] -> A in [1,2^30], product <= 2^120 < f32 max.
// Spill tripwire: WRITE_SIZE >= 120MB -> revert to R18.

typedef __attribute__((ext_vector_type(8))) short bf16x8;
typedef __attribute__((ext_vector_type(4))) float f32x4;
typedef __attribute__((ext_vector_type(8))) _Float16 h16x8;
typedef __attribute__((ext_vector_type(4))) _Float16 h16x4;

__device__ __forceinline__ unsigned short f2bf(float f) {
  union { float f; unsigned int u; } v; v.f = f;
  return (unsigned short)((v.u + 0x7FFFu + ((v.u >> 16) & 1u)) >> 16);
}

__device__ __forceinline__ unsigned int cvt_pk_bf16(float a, float b) {
  unsigned int r;
  asm("v_cvt_pk_bf16_f32 %0, %1, %2" : "=v"(r) : "v"(a), "v"(b));
  return r;  // lo = bf16(a), hi = bf16(b)
}

// ---- prep (unchanged from R14/R18) ----
__global__ __launch_bounds__(256) void ca_prep_kernel(
    const float* __restrict__ Wqkv, const float* __restrict__ Wout,
    const float* __restrict__ bqkv, const float* __restrict__ bh,
    unsigned short* __restrict__ Wqb_t, unsigned short* __restrict__ Wcb_t,
    float* __restrict__ bcomb, float* __restrict__ bsc) {
  const int blk = blockIdx.x;
  if (blk < 64) {
    const int t = blk * 256 + threadIdx.x;  // 16384 threads
    const int k8 = t >> 9, n = t & 511;
    const float* src = Wqkv + (size_t)n * 256 + k8 * 8;
    const float4 v0 = *(const float4*)src;
    const float4 v1 = *(const float4*)(src + 4);
    bf16x8 o;
    o[0] = (short)f2bf(v0.x); o[1] = (short)f2bf(v0.y);
    o[2] = (short)f2bf(v0.z); o[3] = (short)f2bf(v0.w);
    o[4] = (short)f2bf(v1.x); o[5] = (short)f2bf(v1.y);
    o[6] = (short)f2bf(v1.z); o[7] = (short)f2bf(v1.w);
    *(bf16x8*)(Wqb_t + (size_t)t * 8) = o;
    return;
  }
  const int dp = blk - 64;       // output row n (0..255)
  const int e = threadIdx.x;     // k (0..255)
  if (dp < 2) {                  // bsc[512]: scaled combined bias
    const int n = dp * 256 + e;
    const float b = bqkv[n] + (n < 256 ? bh[n] : 0.f);
    bsc[n] = b * 2.8853900817779268f;  // 2*log2(e)
  }
  const float* wrow = Wout + (size_t)dp * 256;
  float acc = 0.f;
  for (int f = 0; f < 256; ++f)
    acc = fmaf(wrow[f], Wqkv[(size_t)(512 + f) * 256 + e], acc);
  Wcb_t[((size_t)(e >> 3) * 256 + dp) * 8 + (e & 7)] = f2bf(acc);
  if (e == 0) {
    float b = 0.f;
    for (int f = 0; f < 256; ++f) b = fmaf(wrow[f], bqkv[512 + f], b);
    bcomb[dp] = b;
  }
}

// ---- fused: qk MFMA (barrier-free direct-B) + exp + (score || out MFMA) ----
__global__ __launch_bounds__(512, 4) void ca_fused(
    const float* __restrict__ x,               // (8,16,512,256) fp32
    const unsigned short* __restrict__ Wqb_t,  // [32][512][8] bf16
    const unsigned short* __restrict__ Wcb_t,  // [32][256][8] bf16
    const float* __restrict__ bsc,             // 512: (bias)*2log2e
    const float* __restrict__ Vw,
    const float* __restrict__ bcomb, const float* __restrict__ bout,
    float* __restrict__ out) {
  __shared__ __align__(16) unsigned short xs[32 * 264];  // 16.9 KB A tile
  __shared__ __align__(16) unsigned short EsB[16640];    // 33.3 KB Es
  __shared__ __align__(16) float vw_s[256];
  __shared__ float af_s[32];
  _Float16* const Es = (_Float16*)EsB;      // 32 rows x 520 (512 + pad)

  const int tid = threadIdx.x;
  const int lane = tid & 63, wave = tid >> 6;
  const int quad = lane >> 4, l15 = lane & 15;
  const int rt0 = blockIdx.x * 32;          // global xf row base

  if (tid < 256) vw_s[tid] = -2.f * Vw[tid];

  // x tile: 32 rows x 256 fp32 -> bf16 -> xs (row stride 264)
  {
    const int rl = tid >> 4, c0 = (tid & 15) * 16;
    const int r = rt0 + rl;
    const int b = r >> 13, l = (r >> 4) & 511, c = r & 15;
    const float* src = x + ((size_t)(b * 16 + c) * 512 + l) * 256 + c0;
    unsigned short* dst = xs + rl * 264 + c0;
#pragma unroll
    for (int j = 0; j < 2; ++j) {
      const float4 v0 = *(const float4*)(src + j * 8);
      const float4 v1 = *(const float4*)(src + j * 8 + 4);
      uint4 o;
      o.x = cvt_pk_bf16(v0.x, v0.y);
      o.y = cvt_pk_bf16(v0.z, v0.w);
      o.z = cvt_pk_bf16(v1.x, v1.y);
      o.w = cvt_pk_bf16(v1.z, v1.w);
      *(uint4*)(dst + j * 8) = o;
    }
  }
  __syncthreads();  // xs + vw_s ready

  // ---------- stage 1: E[32 x 512], BARRIER-FREE depth-2 streaming ----------
  f32x4 acc[2][4] = {};
  {
    const unsigned short* b1 = Wqb_t + quad * 4096 + (wave * 64 + l15) * 8;
    bf16x8 bb[3][4];
#pragma unroll
    for (int s = 0; s < 2; ++s)
#pragma unroll
      for (int ni = 0; ni < 4; ++ni)
        bb[s][ni] = *(const bf16x8*)(b1 + (size_t)s * 16384 + ni * 128);
#pragma unroll
    for (int c = 0; c < 8; ++c) {
      if (c + 2 < 8) {
#pragma unroll
        for (int ni = 0; ni < 4; ++ni)
          bb[(c + 2) % 3][ni] =
              *(const bf16x8*)(b1 + (size_t)(c + 2) * 16384 + ni * 128);
      }
      bf16x8 af[2];
#pragma unroll
      for (int mi = 0; mi < 2; ++mi)
        af[mi] = *(const bf16x8*)&xs[(mi * 16 + l15) * 264 + c * 32 + quad * 8];
#pragma unroll
      for (int mi = 0; mi < 2; ++mi)
#pragma unroll
        for (int ni = 0; ni < 4; ++ni)
          acc[mi][ni] = __builtin_amdgcn_mfma_f32_16x16x32_bf16(
              bb[c % 3][ni], af[mi], acc[mi][ni], 0, 0, 0);
    }
  }

  // stage-1 epilogue: E = exp2(clamp(acc*2log2e + bsc, +-15)) -> Es
  const float SC = 2.8853900817779268f;  // 2*log2(e)
#pragma unroll
  for (int mi = 0; mi < 2; ++mi) {
    const int rl = mi * 16 + l15;
#pragma unroll
    for (int ni = 0; ni < 4; ++ni) {
      const int n = wave * 64 + ni * 16 + quad * 4;
      const float4 bs = *(const float4*)(bsc + n);
      h16x4 st;
      st[0] = (_Float16)__builtin_amdgcn_exp2f(
          fminf(15.f, fmaxf(-15.f, fmaf(acc[mi][ni][0], SC, bs.x))));
      st[1] = (_Float16)__builtin_amdgcn_exp2f(
          fminf(15.f, fmaxf(-15.f, fmaf(acc[mi][ni][1], SC, bs.y))));
      st[2] = (_Float16)__builtin_amdgcn_exp2f(
          fminf(15.f, fmaxf(-15.f, fmaf(acc[mi][ni][2], SC, bs.z))));
      st[3] = (_Float16)__builtin_amdgcn_exp2f(
          fminf(15.f, fmaxf(-15.f, fmaf(acc[mi][ni][3], SC, bs.w))));
      *(h16x4*)&Es[rl * 520 + n] = st;
    }
  }
  __syncthreads();  // Es visible to all waves

  // ---------- fused: score (VALU, batched rcp) || stage 2 (MFMA) ----------
  f32x4 acc2[2][2] = {};
  {
    const int p = tid >> 8, qc = (tid >> 4) & 15, kc = tid & 15;
    const _Float16* eqp = Es + (p * 16 + qc) * 520;
    const _Float16* ekp = Es + (p * 16 + kc) * 520 + 256;
    const unsigned short* wb2 = Wcb_t + (size_t)(quad * 256 + wave * 32 + l15) * 8;
    bf16x8 bcur0 = *(const bf16x8*)(wb2);
    bf16x8 bcur1 = *(const bf16x8*)(wb2 + 128);
    float asum = 0.f;
#pragma unroll
    for (int c = 0; c < 8; ++c) {
      bf16x8 bnxt0, bnxt1;
      if (c < 7) {  // prefetch next chunk's B-frags (covered by score VALU)
        bnxt0 = *(const bf16x8*)(wb2 + (size_t)(c + 1) * 8192);
        bnxt1 = *(const bf16x8*)(wb2 + (size_t)(c + 1) * 8192 + 128);
      }
      bf16x8 af0 = *(const bf16x8*)&xs[l15 * 264 + c * 32 + quad * 8];
      bf16x8 af1 = *(const bf16x8*)&xs[(16 + l15) * 264 + c * 32 + quad * 8];
      // 4 score iterations over d = 32c .. 32c+31: scalar-f32 front,
      // 4-way batched reciprocal (1 rcp per 4 elements)
#pragma unroll
      for (int j = 0; j < 4; ++j) {
        const int d = c * 32 + j * 8;
        const h16x8 eq = *(const h16x8*)(eqp + d);
        const h16x8 ek = *(const h16x8*)(ekp + d);
        const f32x4 wv0 = *(const f32x4*)(vw_s + d);
        const f32x4 wv1 = *(const f32x4*)(vw_s + d + 4);
        {
          const float A0 = fmaf((float)eq[0], (float)ek[0], 1.f);
          const float A1 = fmaf((float)eq[1], (float)ek[1], 1.f);
          const float A2 = fmaf((float)eq[2], (float)ek[2], 1.f);
          const float A3 = fmaf((float)eq[3], (float)ek[3], 1.f);
          const float P01 = A0 * A1, P23 = A2 * A3;
          const float i1 = fmaf(wv0.y, A0, wv0.x * A1);
          const float i2 = fmaf(wv0.w, A2, wv0.z * A3);
          const float num = fmaf(i2, P01, i1 * P23);
          asum = fmaf(num, __builtin_amdgcn_rcpf(P01 * P23), asum);
        }
        {
          const float A4 = fmaf((float)eq[4], (float)ek[4], 1.f);
          const float A5 = fmaf((float)eq[5], (float)ek[5], 1.f);
          const float A6 = fmaf((float)eq[6], (float)ek[6], 1.f);
          const float A7 = fmaf((float)eq[7], (float)ek[7], 1.f);
          const float P45 = A4 * A5, P67 = A6 * A7;
          const float i1 = fmaf(wv1.y, A4, wv1.x * A5);
          const float i2 = fmaf(wv1.w, A6, wv1.z * A7);
          const float num = fmaf(i2, P45, i1 * P67);
          asum = fmaf(num, __builtin_amdgcn_rcpf(P45 * P67), asum);
        }
      }
      // 4 MFMAs for stage2 chunk c (separate pipe; overlaps score VALU)
      acc2[0][0] = __builtin_amdgcn_mfma_f32_16x16x32_bf16(bcur0, af0, acc2[0][0], 0, 0, 0);
      acc2[0][1] = __builtin_amdgcn_mfma_f32_16x16x32_bf16(bcur1, af0, acc2[0][1], 0, 0, 0);
      acc2[1][0] = __builtin_amdgcn_mfma_f32_16x16x32_bf16(bcur0, af1, acc2[1][0], 0, 0, 0);
      acc2[1][1] = __builtin_amdgcn_mfma_f32_16x16x32_bf16(bcur1, af1, acc2[1][1], 0, 0, 0);
      bcur0 = bnxt0; bcur1 = bnxt1;
    }
    // score reduction + diagonal softmax weight
    float s = asum;
    float m = s;
    for (int off = 8; off; off >>= 1) m = fmaxf(m, __shfl_xor(m, off, 16));
    const float e = __builtin_amdgcn_exp2f((s - m) * 1.4426950408889634f);
    float sum = e;
    for (int off = 8; off; off >>= 1) sum += __shfl_xor(sum, off, 16);
    if (kc == qc) af_s[p * 16 + qc] = e / sum;
  }
  __syncthreads();  // af_s visible to all waves

  // stage-2 epilogue: out = a*(acc2+bcomb)+bout, permuted (b,c,l,d) store
#pragma unroll
  for (int mi = 0; mi < 2; ++mi) {
    const int rl = mi * 16 + l15;
    const int r = rt0 + rl;
    const int c = r & 15, p = r >> 4;
    const int l = p & 511, b = p >> 9;
    const float av = af_s[rl];
    float* orow = out + ((size_t)(b * 16 + c) * 512 + l) * 256;
#pragma unroll
    for (int ni = 0; ni < 2; ++ni) {
      const int n = wave * 32 + ni * 16 + quad * 4;
      const float4 bc = *(const float4*)(bcomb + n);
      const float4 bo = *(const float4*)(bout + n);
      float4 o;
      o.x = fmaf(av, acc2[mi][ni][0] + bc.x, bo.x);
      o.y = fmaf(av, acc2[mi][ni][1] + bc.y, bo.y);
      o.z = fmaf(av, acc2[mi][ni][2] + bc.z, bo.z);
      o.w = fmaf(av, acc2[mi][ni][3] + bc.w, bo.w);
      *(float4*)(orow + n) = o;
    }
  }
}

extern "C" void kernel_launch(void* const* d_in, const int* in_sizes, int n_in,
                              void* d_out, int out_size, void* d_ws, size_t ws_size,
                              hipStream_t stream) {
  (void)in_sizes; (void)n_in; (void)out_size; (void)ws_size;
  const float* x    = (const float*)d_in[0];
  const float* Wqkv = (const float*)d_in[1];
  const float* bqkv = (const float*)d_in[2];
  const float* Vw   = (const float*)d_in[3];
  const float* bh   = (const float*)d_in[5];
  const float* Wout = (const float*)d_in[7];
  const float* bout = (const float*)d_in[8];
  float* out = (float*)d_out;

  // ws: bcomb f32 256 | bsc f32 512 | Wqb_t bf16 512*256 | Wcb_t bf16 256*256
  float* bcomb = (float*)d_ws;
  float* bsc = bcomb + 256;
  unsigned short* Wqb_t = (unsigned short*)(bsc + 512);
  unsigned short* Wcb_t = Wqb_t + (size_t)512 * 256;

  ca_prep_kernel<<<dim3(320), dim3(256), 0, stream>>>(
      Wqkv, Wout, bqkv, bh, Wqb_t, Wcb_t, bcomb, bsc);
  ca_fused<<<dim3(2048), dim3(512), 0, stream>>>(
      x, Wqb_t, Wcb_t, bsc, Vw, bcomb, bout, out);
}